// Round 16
// baseline (995.472 us; speedup 1.0000x reference)
//
#include <hip/hip_runtime.h>
#include <math.h>

#define NB 32
#define NP 24656
#define NO 16
#define NC 81
#define ND 85   // 4 + NC
#define THRESH_F 0.5f
#define NEGPOS_I 3
#define VAR0_F 0.1f
#define VAR1_F 0.2f
#define NEG_HUGE -1e30f

#define BPCNT (NB * NP)
#define MBLK2 25         // k_match blocks per batch row = ceil(NP/1024)
#define CHB32 771        // 32-row chunks per batch row = ceil(NP/32)
#define SPB2 56          // k_main blocks per batch row (56*32 = 1792 = 7/CU)
#define CB32 11264       // staged bytes per chunk = 11 x 1024 (>= 32*85*4)

typedef unsigned long long u64;

// ---------------------------------------------------------------- match body
template <bool INIT>
__device__ __forceinline__ void match_body(
    const float* __restrict__ tb,  // LDS truth boxes
    const float* __restrict__ priors,
    float2* __restrict__ bt2, u64* __restrict__ mcand,
    int b, int bx, int tid, u64 (*wkey)[NO]) {
    const int lane = tid & 63, wv = tid >> 6;
    const int p0 = bx * 1024 + tid * 4;
    float pl[4], pt[4], prr[4], pbm[4], pa[4];
    bool pv[4];
#pragma unroll
    for (int j = 0; j < 4; ++j) {
        const int p = p0 + j;
        pv[j] = (p < NP);
        const float4 q = pv[j] ? ((const float4*)priors)[p]
                               : make_float4(0.f, 0.f, 1.f, 1.f);
        pl[j] = q.x - q.z * 0.5f; pt[j] = q.y - q.w * 0.5f;
        prr[j] = q.x + q.z * 0.5f; pbm[j] = q.y + q.w * 0.5f;
        pa[j] = (prr[j] - pl[j]) * (pbm[j] - pt[j]);
    }
    float bestv[4] = {-1.f, -1.f, -1.f, -1.f};
    int besti[4] = {0, 0, 0, 0};
    for (int o = 0; o < NO; ++o) {
        const float al = tb[o * 4], at = tb[o * 4 + 1];
        const float ar = tb[o * 4 + 2], ab = tb[o * 4 + 3];
        const float aarea = (ar - al) * (ab - at);
        u64 kmax = 0ull;
#pragma unroll
        for (int j = 0; j < 4; ++j) {
            float iw = fminf(ar, prr[j]) - fmaxf(al, pl[j]); iw = fmaxf(iw, 0.f);
            float ih = fminf(ab, pbm[j]) - fmaxf(at, pt[j]); ih = fmaxf(ih, 0.f);
            const float inter = iw * ih;
            const float iou = inter / (aarea + pa[j] - inter);
            if (pv[j]) {
                if (iou > bestv[j]) { bestv[j] = iou; besti[j] = o; }
                const u64 key = ((u64)__float_as_uint(iou) << 32) |
                                (u64)(0xFFFFFFFFu - (unsigned)(p0 + j));
                kmax = (key > kmax) ? key : kmax;
            }
        }
        for (int d = 1; d < 64; d <<= 1) {
            const u64 other = __shfl_xor(kmax, d, 64);
            kmax = (other > kmax) ? other : kmax;
        }
        if (lane == 0) wkey[wv][o] = kmax;
    }
#pragma unroll
    for (int j = 0; j < 4; ++j)
        if (pv[j])
            bt2[(size_t)b * NP + p0 + j] =
                make_float2(bestv[j], __int_as_float(besti[j]));
    __syncthreads();
    if (tid < NO) {
        u64 k0 = wkey[0][tid];
        k0 = (wkey[1][tid] > k0) ? wkey[1][tid] : k0;
        k0 = (wkey[2][tid] > k0) ? wkey[2][tid] : k0;
        k0 = (wkey[3][tid] > k0) ? wkey[3][tid] : k0;
        mcand[((size_t)(b * NO + tid)) * MBLK2 + bx] = k0;
    }
}

// ---------------------------------------------------------------- match
__global__ __launch_bounds__(256) void k_match(
    const float* __restrict__ tboxes, const float* __restrict__ priors,
    float2* __restrict__ bt2, u64* __restrict__ mcand,
    int* __restrict__ npos, float* __restrict__ accB, int* __restrict__ done) {
    const int b = blockIdx.y, bx = blockIdx.x, tid = threadIdx.x;
    __shared__ float tb[NO * 4];
    __shared__ u64 wkey[4][NO];
    if (bx == 0 && b == 0) {  // merged k_init
        if (tid < NB) npos[tid] = 0;
        if (tid < 2 * NB) accB[tid] = 0.f;
        if (tid == 0) *done = 0;
    }
    if (tid < NO * 4) tb[tid] = tboxes[b * NO * 4 + tid];
    __syncthreads();
    match_body<true>(tb, priors, bt2, mcand, b, bx, tid, wkey);
}

// ---------------------------------------------------------------- match PROBE
// DIAGNOSTIC: identical work x32 reps into dummies -> appears in top-5 with
// its own dur_us. m = dur/32.
__global__ __launch_bounds__(256) void k_match_probe(
    const float* __restrict__ tboxes, const float* __restrict__ priors,
    float2* __restrict__ bt2d, u64* __restrict__ mcandd) {
    const int b = blockIdx.y, bx = blockIdx.x, tid = threadIdx.x;
    __shared__ float tb[NO * 4];
    __shared__ u64 wkey[4][NO];
    if (tid < NO * 4) tb[tid] = tboxes[b * NO * 4 + tid];
    __syncthreads();
    for (int rep = 0; rep < 32; ++rep) {
        match_body<false>(tb, priors, bt2d, mcandd, b, bx, tid, wkey);
        __syncthreads();
    }
}

// ---------------------------------------------------------------- stage (reg)
__device__ __forceinline__ void stage_load(float4* vreg,
                                           const char* __restrict__ gpred,
                                           int b, int r0, int lane) {
    const size_t off = ((size_t)b * NP + r0) * 340ull;
    const char* g = gpred + off;
    const bool unsafe = (b == NB - 1) && (r0 + 34 > NP);
    if (!unsafe) {
#pragma unroll
        for (int k = 0; k < 11; ++k)
            vreg[k] = *(const float4*)(g + k * 1024 + lane * 16);
    } else {
        const int nf4 = (NP - r0) * ND / 4;  // tail: 16 rows -> 340 float4
        const float4* gs = (const float4*)g;
#pragma unroll
        for (int k = 0; k < 11; ++k) {
            const int idx = k * 64 + lane;
            vreg[k] = (idx < nf4) ? gs[idx]
                                  : make_float4(0.f, 0.f, 0.f, 0.f);
        }
    }
}

__device__ __forceinline__ void stage_write(char* buf, const float4* vreg,
                                            int lane) {
#pragma unroll
    for (int k = 0; k < 11; ++k)
        *(float4*)(buf + k * 1024 + lane * 16) = vreg[k];
}

// ---------------------------------------------------------------- main fused
__global__ __launch_bounds__(64) void k_main(
    const float* __restrict__ pred, const float* __restrict__ tboxes,
    const int* __restrict__ tlabels, const float* __restrict__ priors,
    const float2* __restrict__ bt2, const u64* __restrict__ mcand,
    float* __restrict__ lr, int* __restrict__ npos, float* __restrict__ accB) {
    __shared__ char smem[2][CB32];

    const int b = blockIdx.y;
    const int span = blockIdx.x;
    const int lane = threadIdx.x;
    const size_t bbase = (size_t)b * NP;
    const char* gpred = (const char*)pred;

    char* cur = smem[0];
    char* nxt = smem[1];

    const int rho = lane >> 1;   // row in chunk 0..31
    const int h = lane & 1;      // half: 0 -> slots 1..11, 1 -> slots 11..21
    const int c0 = rho & 3;
    const int Ab = 16 * (21 * rho + (rho >> 2));  // byte of aligned slot 0
    const int sbase = h ? 11 : 1;

    // prologue: per-o best prior for this b (lanes 0..15), broadcast to all
    u64 pbk = 0ull;
    if (lane < NO) {
        const u64* c = mcand + (size_t)(b * NO + lane) * MBLK2;
        for (int i = 0; i < MBLK2; ++i) {
            const u64 v = c[i];
            pbk = (v > pbk) ? v : pbk;
        }
    }
    int p16[NO];
#pragma unroll
    for (int j = 0; j < NO; ++j) {
        const u64 kj = __shfl(pbk, j, 64);
        p16[j] = (int)(0xFFFFFFFFu - (unsigned)(kj & 0xFFFFFFFFull));
    }

    float my_ll = 0.f, my_ce = 0.f;
    int my_np = 0;

    int chunk = span;
    int next_chunk = chunk + SPB2;
    {
        float4 vreg[11];
        stage_load(vreg, gpred, b, chunk * 32, lane);
        stage_write(cur, vreg, lane);
    }

    while (chunk < CHB32) {
        float4 vreg[11];
        const bool have_next = (next_chunk < CHB32);
        if (have_next)
            stage_load(vreg, gpred, b, next_chunk * 32, lane);  // issue early

        const int r0 = chunk * 32;
        const int nrows = min(32, NP - r0);

        float4 v[11];
#pragma unroll
        for (int k = 0; k < 11; ++k)
            v[k] = *(const float4*)(cur + Ab + 16 * (sbase + k));

        float vals[44];
#pragma unroll
        for (int k = 0; k < 11; ++k) {
            const float xs[4] = {v[k].x, v[k].y, v[k].z, v[k].w};
#pragma unroll
            for (int t = 0; t < 4; ++t) {
                bool ok;
                if (k == 0)
                    ok = h ? false : (t >= c0);
                else if (k == 10)
                    ok = h ? (t <= c0) : true;
                else
                    ok = true;
                vals[4 * k + t] = ok ? xs[t] : NEG_HUGE;
            }
        }
        float mA = vals[0], mB = vals[1];
#pragma unroll
        for (int j = 2; j < 44; j += 2) {
            mA = fmaxf(mA, vals[j]);
            mB = fmaxf(mB, vals[j + 1]);
        }
        float m = fmaxf(mA, mB);
        m = fmaxf(m, __shfl_xor(m, 1, 64));  // pair (row) max

        float sA = 0.f, sB = 0.f;
#pragma unroll
        for (int j = 0; j < 44; j += 2) {
            sA += __expf(vals[j] - m);
            sB += __expf(vals[j + 1] - m);
        }
        float ssum = sA + sB;
        ssum += __shfl_xor(ssum, 1, 64);     // pair (row) sum
        const float lse = m + __logf(ssum);

        if (h == 0 && rho < nrows) {
            const float bg = (c0 == 0) ? v[0].x : (c0 == 1) ? v[0].y
                           : (c0 == 2) ? v[0].z : v[0].w;  // slot1 comp c0
            const int p = r0 + rho;
            const float2 bt = bt2[bbase + p];
            int o_f = -1;
#pragma unroll
            for (int j = 0; j < NO; ++j)
                if (p == p16[j]) o_f = j;   // ascending j = last-o-wins
            const bool forced = (o_f >= 0);
            const bool pos = forced || (bt.x >= THRESH_F);
            const int o = forced ? o_f : __float_as_int(bt.y);
            lr[bbase + p] = pos ? 0.f : (lse - bg);
            if (pos) {
                my_np += 1;
                const float* rowp = (const float*)(cur + 340 * rho);
                const int lbl = tlabels[b * NO + o] + 1;
                my_ce += lse - rowp[4 + lbl];
                const float4 pq = *((const float4*)priors + p);
                const float tx0 = tboxes[(b * NO + o) * 4 + 0];
                const float ty0 = tboxes[(b * NO + o) * 4 + 1];
                const float tx1 = tboxes[(b * NO + o) * 4 + 2];
                const float ty1 = tboxes[(b * NO + o) * 4 + 3];
                const float g0 = ((tx0 + tx1) * 0.5f - pq.x) / (VAR0_F * pq.z);
                const float g1 = ((ty0 + ty1) * 0.5f - pq.y) / (VAR0_F * pq.w);
                const float g2 = __logf((tx1 - tx0) / pq.z) / VAR1_F;
                const float g3 = __logf((ty1 - ty0) / pq.w) / VAR1_F;
                float dd, ad;
                dd = rowp[0] - g0; ad = fabsf(dd); my_ll += (ad < 1.f) ? 0.5f * dd * dd : (ad - 0.5f);
                dd = rowp[1] - g1; ad = fabsf(dd); my_ll += (ad < 1.f) ? 0.5f * dd * dd : (ad - 0.5f);
                dd = rowp[2] - g2; ad = fabsf(dd); my_ll += (ad < 1.f) ? 0.5f * dd * dd : (ad - 0.5f);
                dd = rowp[3] - g3; ad = fabsf(dd); my_ll += (ad < 1.f) ? 0.5f * dd * dd : (ad - 0.5f);
            }
        }

        if (have_next)
            stage_write(nxt, vreg, lane);    // write late (vmcnt drain here)

        chunk = next_chunk;
        next_chunk += SPB2;
        char* tmp = cur; cur = nxt; nxt = tmp;
    }

    for (int d2 = 1; d2 < 64; d2 <<= 1) {
        my_ll += __shfl_xor(my_ll, d2, 64);
        my_ce += __shfl_xor(my_ce, d2, 64);
        my_np += __shfl_xor(my_np, d2, 64);
    }
    if (lane == 0) {
        if (my_ll != 0.f) atomicAdd(&accB[b * 2 + 0], my_ll);
        if (my_ce != 0.f) atomicAdd(&accB[b * 2 + 1], my_ce);
        if (my_np) atomicAdd(&npos[b], my_np);
    }
}

// ---------------------------------------------------------------- select body
__device__ __forceinline__ float select_body(
    const float4* __restrict__ row4, int K0, int tid, int lane, int wid,
    int sub, unsigned (*hist16)[16], unsigned* chist, int* sh_bucket,
    int* sh_knew, float* wsum, int* wcnt) {
    int k = K0;
    unsigned prefix = 0;
    const int shifts[3] = {21, 10, 0};
    const unsigned masks[3] = {0u, 0xFFE00000u, 0xFFFFFC00u};

    for (int pass = 0; pass < 3; ++pass) {
        const int shift = shifts[pass];
        const unsigned mask_hi = masks[pass];
        {
            unsigned* hflat = (unsigned*)hist16;
            for (int j = tid; j < 2048 * 16; j += 1024) hflat[j] = 0;
        }
        __syncthreads();
        for (int i = tid; i < NP / 4; i += 1024) {
            const float4 v4 = row4[i];
#pragma unroll
            for (int c = 0; c < 4; ++c) {
                const float f = (c == 0) ? v4.x : (c == 1) ? v4.y
                              : (c == 2) ? v4.z : v4.w;
                const unsigned v = __float_as_uint(f);
                if ((v & mask_hi) == (prefix & mask_hi))
                    atomicAdd(&hist16[(v >> shift) & 2047u][sub], 1u);
            }
        }
        __syncthreads();
        for (int j = tid; j < 2048; j += 1024) {
            unsigned t = 0;
#pragma unroll
            for (int s = 0; s < 16; ++s) t += hist16[j][s];
            chist[j] = t;
        }
        __syncthreads();
        if (tid < 64) {
            unsigned g = 0;
            for (int j = 0; j < 32; ++j) g += chist[lane * 32 + j];
            unsigned T = g;
            for (int d = 1; d < 64; d <<= 1) {
                const unsigned t = __shfl_down(T, d, 64);
                if (lane + d < 64) T += t;
            }
            const unsigned E = T - g;
            const bool hit = (E < (unsigned)k) && ((unsigned)k <= T);
            const unsigned long long msk = __ballot(hit);
            const int wl = __ffsll(msk) - 1;
            if (lane == wl) {
                unsigned cum = E;
                int bsel = lane * 32, kn = k;
                for (int j = 31; j >= 0; --j) {
                    const unsigned c = chist[lane * 32 + j];
                    if (cum + c >= (unsigned)k) {
                        bsel = lane * 32 + j;
                        kn = k - (int)cum;
                        break;
                    }
                    cum += c;
                }
                *sh_bucket = bsel;
                *sh_knew = kn;
            }
        }
        __syncthreads();
        prefix |= ((unsigned)(*sh_bucket)) << shift;
        k = *sh_knew;
        __syncthreads();
    }
    const float T = __uint_as_float(prefix);

    float msum = 0.f;
    int mcnt = 0;
    for (int i = tid; i < NP / 4; i += 1024) {
        const float4 v4 = row4[i];
#pragma unroll
        for (int c = 0; c < 4; ++c) {
            const float f = (c == 0) ? v4.x : (c == 1) ? v4.y
                          : (c == 2) ? v4.z : v4.w;
            if (__float_as_uint(f) > prefix) { msum += f; mcnt++; }
        }
    }
    for (int s = 32; s > 0; s >>= 1) {
        msum += __shfl_down(msum, s, 64);
        mcnt += __shfl_down(mcnt, s, 64);
    }
    if (lane == 0) { wsum[wid] = msum; wcnt[wid] = mcnt; }
    __syncthreads();
    float negsum = 0.f;
    if (tid == 0) {
        float tot = 0.f;
        int cnt = 0;
        for (int w = 0; w < 16; ++w) { tot += wsum[w]; cnt += wcnt[w]; }
        negsum = tot + (float)(K0 - cnt) * T;
    }
    __syncthreads();
    return negsum;
}

// ---------------------------------------------------------------- select
__global__ __launch_bounds__(1024) void k_select(
    const float* __restrict__ lrk, const int* __restrict__ npos,
    float* __restrict__ accB, int* __restrict__ done, float* __restrict__ out) {
    const int b = blockIdx.x;
    const float4* row4 = (const float4*)(lrk + (size_t)b * NP);
    const int tid = threadIdx.x;
    const int lane = tid & 63;
    const int wid = tid >> 6;
    const int sub = lane & 15;

    __shared__ unsigned hist16[2048][16];  // 128 KiB, [bin][sub]
    __shared__ unsigned chist[2048];       // 8 KiB
    __shared__ int sh_bucket, sh_knew;
    __shared__ float wsum[16];
    __shared__ int wcnt[16];

    const int K0 = min(npos[b] * NEGPOS_I, NP);
    const float negsum = select_body(row4, K0, tid, lane, wid, sub, hist16,
                                     chist, &sh_bucket, &sh_knew, wsum, wcnt);
    if (tid == 0) {
        atomicAdd(&accB[b * 2 + 1], negsum);
        __threadfence();
        if (atomicAdd(done, 1) == NB - 1) {   // merged k_final
            volatile const float* va = accB;
            volatile const int* vn = npos;
            int n = 0;
            float a0 = 0.f, a1 = 0.f;
            for (int bb = 0; bb < NB; ++bb) {
                n += vn[bb];
                a0 += va[bb * 2 + 0];
                a1 += va[bb * 2 + 1];
            }
            const float N = (float)n;
            out[0] = a0 / N;
            out[1] = a1 / N;
        }
    }
}

// ---------------------------------------------------------------- select PROBE
// DIAGNOSTIC: identical work x16 reps into dummy accumulator. s = dur/16.
__global__ __launch_bounds__(1024) void k_select_probe(
    const float* __restrict__ lrk, const int* __restrict__ npos,
    float* __restrict__ accB2) {
    const int b = blockIdx.x;
    const float4* row4 = (const float4*)(lrk + (size_t)b * NP);
    const int tid = threadIdx.x;
    const int lane = tid & 63;
    const int wid = tid >> 6;
    const int sub = lane & 15;

    __shared__ unsigned hist16[2048][16];
    __shared__ unsigned chist[2048];
    __shared__ int sh_bucket, sh_knew;
    __shared__ float wsum[16];
    __shared__ int wcnt[16];

    const int K0 = min(npos[b] * NEGPOS_I, NP);
    for (int rep = 0; rep < 16; ++rep) {
        const float negsum = select_body(row4, K0, tid, lane, wid, sub, hist16,
                                         chist, &sh_bucket, &sh_knew, wsum,
                                         wcnt);
        if (tid == 0) atomicAdd(&accB2[b * 2 + 1], negsum);
        __syncthreads();
    }
}

extern "C" void kernel_launch(void* const* d_in, const int* in_sizes, int n_in,
                              void* d_out, int out_size, void* d_ws, size_t ws_size,
                              hipStream_t stream) {
    const float* pred   = (const float*)d_in[0];
    const float* tboxes = (const float*)d_in[1];
    const int*   tlabels = (const int*)d_in[2];
    const float* priors = (const float*)d_in[3];
    float* out = (float*)d_out;

    char* w = (char*)d_ws;
    float2* bt2 = (float2*)w;                         // 8*BPCNT bytes
    float*  lrk = (float*)(w + 8ull * BPCNT);         // 4*BPCNT bytes
    u64*    mcand = (u64*)(w + 12ull * BPCNT);        // NB*NO*MBLK2 u64 (100 KB)
    char*   w2 = w + 12ull * BPCNT + 8ull * NB * NO * MBLK2;
    int*    npos = (int*)w2;                          // NB i32
    float*  accB = (float*)(w2 + 4ull * NB);          // NB*2 f32
    int*    done = (int*)(w2 + 4ull * NB + 8ull * NB); // 1 i32
    // ---- diagnostic dummies (far region of 1 GiB ws, never read) ----
    char*   wd = w + (64ull << 20);
    float2* bt2d   = (float2*)wd;                          // 8*BPCNT
    u64*    mcandd = (u64*)(wd + 8ull * BPCNT);            // 100 KB
    float*  accB2  = (float*)(wd + 8ull * BPCNT + 8ull * NB * NO * MBLK2);

    k_match<<<dim3(MBLK2, NB), dim3(256), 0, stream>>>(
        tboxes, priors, bt2, mcand, npos, accB, done);
    // PROBE: match x32 (dummy outputs) -> top-5 row; m = dur/32
    k_match_probe<<<dim3(MBLK2, NB), dim3(256), 0, stream>>>(
        tboxes, priors, bt2d, mcandd);
    k_main<<<dim3(SPB2, NB), dim3(64), 0, stream>>>(
        pred, tboxes, tlabels, priors, bt2, mcand, lrk, npos, accB);
    // PROBE: select x16 (dummy accumulator) -> top-5 row; s = dur/16
    k_select_probe<<<dim3(NB), dim3(1024), 0, stream>>>(lrk, npos, accB2);
    k_select<<<dim3(NB), dim3(1024), 0, stream>>>(lrk, npos, accB, done, out);
}

// Round 17
// 107.792 us; speedup vs baseline: 9.2351x; 9.2351x over previous
//
#include <hip/hip_runtime.h>
#include <math.h>

#define NB 32
#define NP 24656
#define NO 16
#define NC 81
#define ND 85   // 4 + NC
#define THRESH_F 0.5f
#define NEGPOS_I 3
#define VAR0_F 0.1f
#define VAR1_F 0.2f
#define NEG_HUGE -1e30f

#define BPCNT (NB * NP)
#define MBLK2 25         // k_match blocks per batch row = ceil(NP/1024)
#define CHB32 771        // 32-row chunks per batch row = ceil(NP/32)
#define SPB2 56          // k_main blocks per batch row (56*32 = 1792 = 7/CU)
#define CB32 11264       // staged bytes per chunk = 11 x 1024 (>= 32*85*4)

typedef unsigned long long u64;

// ---------------------------------------------------------------- match
// R17: per-o wave-shuffle reduce (192 ds_bpermute/thread, measured 20 us via
// R16 probe) replaced by LDS tree-reduce (~34 DS ops/thread). Thread computes
// its own per-o kmax in registers, writes kbuf[o][tid]; stage B: thread
// (o,seg) reduces strided subset kbuf[o][i*16+seg] (4-way bank alias = free);
// stage C: 16 lanes finish 16 partials -> mcand.
__global__ __launch_bounds__(256) void k_match(
    const float* __restrict__ tboxes, const float* __restrict__ priors,
    float2* __restrict__ bt2, u64* __restrict__ mcand,
    int* __restrict__ npos, float* __restrict__ accB, int* __restrict__ done) {
    const int b = blockIdx.y, bx = blockIdx.x, tid = threadIdx.x;
    __shared__ float tb[NO * 4];
    __shared__ u64 kbuf[NO][256];   // 32 KiB
    __shared__ u64 pbuf[NO][16];    // 2 KiB
    if (bx == 0 && b == 0) {  // merged k_init
        if (tid < NB) npos[tid] = 0;
        if (tid < 2 * NB) accB[tid] = 0.f;
        if (tid == 0) *done = 0;
    }
    if (tid < NO * 4) tb[tid] = tboxes[b * NO * 4 + tid];
    __syncthreads();

    const int p0 = bx * 1024 + tid * 4;
    float pl[4], pt[4], prr[4], pbm[4], pa[4];
    bool pv[4];
#pragma unroll
    for (int j = 0; j < 4; ++j) {
        const int p = p0 + j;
        pv[j] = (p < NP);
        const float4 q = pv[j] ? ((const float4*)priors)[p]
                               : make_float4(0.f, 0.f, 1.f, 1.f);
        pl[j] = q.x - q.z * 0.5f; pt[j] = q.y - q.w * 0.5f;
        prr[j] = q.x + q.z * 0.5f; pbm[j] = q.y + q.w * 0.5f;
        pa[j] = (prr[j] - pl[j]) * (pbm[j] - pt[j]);
    }
    float bestv[4] = {-1.f, -1.f, -1.f, -1.f};
    int besti[4] = {0, 0, 0, 0};
    for (int o = 0; o < NO; ++o) {
        const float al = tb[o * 4], at = tb[o * 4 + 1];
        const float ar = tb[o * 4 + 2], ab = tb[o * 4 + 3];
        const float aarea = (ar - al) * (ab - at);
        u64 kmax = 0ull;
#pragma unroll
        for (int j = 0; j < 4; ++j) {
            float iw = fminf(ar, prr[j]) - fmaxf(al, pl[j]); iw = fmaxf(iw, 0.f);
            float ih = fminf(ab, pbm[j]) - fmaxf(at, pt[j]); ih = fmaxf(ih, 0.f);
            const float inter = iw * ih;
            const float iou = inter / (aarea + pa[j] - inter);
            if (pv[j]) {
                if (iou > bestv[j]) { bestv[j] = iou; besti[j] = o; }
                const u64 key = ((u64)__float_as_uint(iou) << 32) |
                                (u64)(0xFFFFFFFFu - (unsigned)(p0 + j));
                kmax = (key > kmax) ? key : kmax;
            }
        }
        kbuf[o][tid] = kmax;          // no cross-lane ops
    }
#pragma unroll
    for (int j = 0; j < 4; ++j)
        if (pv[j])
            bt2[(size_t)b * NP + p0 + j] =
                make_float2(bestv[j], __int_as_float(besti[j]));
    __syncthreads();
    {   // stage B: 256 threads = (o, seg); strided subset avoids bank pileup
        const int o = tid >> 4, seg = tid & 15;
        u64 m = kbuf[o][seg];
#pragma unroll
        for (int i = 1; i < 16; ++i) {
            const u64 v = kbuf[o][i * 16 + seg];
            m = (v > m) ? v : m;
        }
        pbuf[o][seg] = m;
    }
    __syncthreads();
    if (tid < NO) {  // stage C
        u64 m = pbuf[tid][0];
#pragma unroll
        for (int i = 1; i < 16; ++i) {
            const u64 v = pbuf[tid][i];
            m = (v > m) ? v : m;
        }
        mcand[((size_t)(b * NO + tid)) * MBLK2 + bx] = m;
    }
}

// ---------------------------------------------------------------- stage (reg)
__device__ __forceinline__ void stage_load(float4* vreg,
                                           const char* __restrict__ gpred,
                                           int b, int r0, int lane) {
    const size_t off = ((size_t)b * NP + r0) * 340ull;
    const char* g = gpred + off;
    const bool unsafe = (b == NB - 1) && (r0 + 34 > NP);
    if (!unsafe) {
#pragma unroll
        for (int k = 0; k < 11; ++k)
            vreg[k] = *(const float4*)(g + k * 1024 + lane * 16);
    } else {
        const int nf4 = (NP - r0) * ND / 4;  // tail: 16 rows -> 340 float4
        const float4* gs = (const float4*)g;
#pragma unroll
        for (int k = 0; k < 11; ++k) {
            const int idx = k * 64 + lane;
            vreg[k] = (idx < nf4) ? gs[idx]
                                  : make_float4(0.f, 0.f, 0.f, 0.f);
        }
    }
}

__device__ __forceinline__ void stage_write(char* buf, const float4* vreg,
                                            int lane) {
#pragma unroll
    for (int k = 0; k < 11; ++k)
        *(float4*)(buf + k * 1024 + lane * 16) = vreg[k];
}

// ---------------------------------------------------------------- main fused
__global__ __launch_bounds__(64) void k_main(
    const float* __restrict__ pred, const float* __restrict__ tboxes,
    const int* __restrict__ tlabels, const float* __restrict__ priors,
    const float2* __restrict__ bt2, const u64* __restrict__ mcand,
    float* __restrict__ lr, int* __restrict__ npos, float* __restrict__ accB) {
    __shared__ char smem[2][CB32];

    const int b = blockIdx.y;
    const int span = blockIdx.x;
    const int lane = threadIdx.x;
    const size_t bbase = (size_t)b * NP;
    const char* gpred = (const char*)pred;

    char* cur = smem[0];
    char* nxt = smem[1];

    const int rho = lane >> 1;   // row in chunk 0..31
    const int h = lane & 1;      // half: 0 -> slots 1..11, 1 -> slots 11..21
    const int c0 = rho & 3;
    const int Ab = 16 * (21 * rho + (rho >> 2));  // byte of aligned slot 0
    const int sbase = h ? 11 : 1;

    // prologue: per-o best prior for this b (lanes 0..15), broadcast to all
    u64 pbk = 0ull;
    if (lane < NO) {
        const u64* c = mcand + (size_t)(b * NO + lane) * MBLK2;
        for (int i = 0; i < MBLK2; ++i) {
            const u64 v = c[i];
            pbk = (v > pbk) ? v : pbk;
        }
    }
    int p16[NO];
#pragma unroll
    for (int j = 0; j < NO; ++j) {
        const u64 kj = __shfl(pbk, j, 64);
        p16[j] = (int)(0xFFFFFFFFu - (unsigned)(kj & 0xFFFFFFFFull));
    }

    float my_ll = 0.f, my_ce = 0.f;
    int my_np = 0;

    int chunk = span;
    int next_chunk = chunk + SPB2;
    {
        float4 vreg[11];
        stage_load(vreg, gpred, b, chunk * 32, lane);
        stage_write(cur, vreg, lane);
    }

    while (chunk < CHB32) {
        float4 vreg[11];
        const bool have_next = (next_chunk < CHB32);
        if (have_next)
            stage_load(vreg, gpred, b, next_chunk * 32, lane);  // issue early

        const int r0 = chunk * 32;
        const int nrows = min(32, NP - r0);

        float4 v[11];
#pragma unroll
        for (int k = 0; k < 11; ++k)
            v[k] = *(const float4*)(cur + Ab + 16 * (sbase + k));

        float vals[44];
#pragma unroll
        for (int k = 0; k < 11; ++k) {
            const float xs[4] = {v[k].x, v[k].y, v[k].z, v[k].w};
#pragma unroll
            for (int t = 0; t < 4; ++t) {
                bool ok;
                if (k == 0)
                    ok = h ? false : (t >= c0);
                else if (k == 10)
                    ok = h ? (t <= c0) : true;
                else
                    ok = true;
                vals[4 * k + t] = ok ? xs[t] : NEG_HUGE;
            }
        }
        float mA = vals[0], mB = vals[1];
#pragma unroll
        for (int j = 2; j < 44; j += 2) {
            mA = fmaxf(mA, vals[j]);
            mB = fmaxf(mB, vals[j + 1]);
        }
        float m = fmaxf(mA, mB);
        m = fmaxf(m, __shfl_xor(m, 1, 64));  // pair (row) max

        float sA = 0.f, sB = 0.f;
#pragma unroll
        for (int j = 0; j < 44; j += 2) {
            sA += __expf(vals[j] - m);
            sB += __expf(vals[j + 1] - m);
        }
        float ssum = sA + sB;
        ssum += __shfl_xor(ssum, 1, 64);     // pair (row) sum
        const float lse = m + __logf(ssum);

        if (h == 0 && rho < nrows) {
            const float bg = (c0 == 0) ? v[0].x : (c0 == 1) ? v[0].y
                           : (c0 == 2) ? v[0].z : v[0].w;  // slot1 comp c0
            const int p = r0 + rho;
            const float2 bt = bt2[bbase + p];
            int o_f = -1;
#pragma unroll
            for (int j = 0; j < NO; ++j)
                if (p == p16[j]) o_f = j;   // ascending j = last-o-wins
            const bool forced = (o_f >= 0);
            const bool pos = forced || (bt.x >= THRESH_F);
            const int o = forced ? o_f : __float_as_int(bt.y);
            lr[bbase + p] = pos ? 0.f : (lse - bg);
            if (pos) {
                my_np += 1;
                const float* rowp = (const float*)(cur + 340 * rho);
                const int lbl = tlabels[b * NO + o] + 1;
                my_ce += lse - rowp[4 + lbl];
                const float4 pq = *((const float4*)priors + p);
                const float tx0 = tboxes[(b * NO + o) * 4 + 0];
                const float ty0 = tboxes[(b * NO + o) * 4 + 1];
                const float tx1 = tboxes[(b * NO + o) * 4 + 2];
                const float ty1 = tboxes[(b * NO + o) * 4 + 3];
                const float g0 = ((tx0 + tx1) * 0.5f - pq.x) / (VAR0_F * pq.z);
                const float g1 = ((ty0 + ty1) * 0.5f - pq.y) / (VAR0_F * pq.w);
                const float g2 = __logf((tx1 - tx0) / pq.z) / VAR1_F;
                const float g3 = __logf((ty1 - ty0) / pq.w) / VAR1_F;
                float dd, ad;
                dd = rowp[0] - g0; ad = fabsf(dd); my_ll += (ad < 1.f) ? 0.5f * dd * dd : (ad - 0.5f);
                dd = rowp[1] - g1; ad = fabsf(dd); my_ll += (ad < 1.f) ? 0.5f * dd * dd : (ad - 0.5f);
                dd = rowp[2] - g2; ad = fabsf(dd); my_ll += (ad < 1.f) ? 0.5f * dd * dd : (ad - 0.5f);
                dd = rowp[3] - g3; ad = fabsf(dd); my_ll += (ad < 1.f) ? 0.5f * dd * dd : (ad - 0.5f);
            }
        }

        if (have_next)
            stage_write(nxt, vreg, lane);    // write late (vmcnt drain here)

        chunk = next_chunk;
        next_chunk += SPB2;
        char* tmp = cur; cur = nxt; nxt = tmp;
    }

    for (int d2 = 1; d2 < 64; d2 <<= 1) {
        my_ll += __shfl_xor(my_ll, d2, 64);
        my_ce += __shfl_xor(my_ce, d2, 64);
        my_np += __shfl_xor(my_np, d2, 64);
    }
    if (lane == 0) {
        if (my_ll != 0.f) atomicAdd(&accB[b * 2 + 0], my_ll);
        if (my_ce != 0.f) atomicAdd(&accB[b * 2 + 1], my_ce);
        if (my_np) atomicAdd(&npos[b], my_np);
    }
}

// ---------------------------------------------------------------- select
// R17: register-cached rows (<=7 float4/thread, static unroll per rule #20)
// -> passes 2/3 + sum pass never re-read memory. uint4-vectorized LDS zero
// (8 stores/thread) and 16-way merge (4 uint4 loads). Sub-slot hist16
// retained (4-way max same-address conflict per wave-instr).
__global__ __launch_bounds__(1024) void k_select(
    const float* __restrict__ lrk, const int* __restrict__ npos,
    float* __restrict__ accB, int* __restrict__ done, float* __restrict__ out) {
    const int b = blockIdx.x;
    const float4* row4 = (const float4*)(lrk + (size_t)b * NP);
    const int tid = threadIdx.x;
    const int lane = tid & 63;
    const int wid = tid >> 6;
    const int sub = lane & 15;

    __shared__ unsigned hist16[2048][16];  // 128 KiB, [bin][sub]
    __shared__ unsigned chist[2048];       // 8 KiB
    __shared__ int sh_bucket, sh_knew;
    __shared__ float wsum[16];
    __shared__ int wcnt[16];

    // register cache of this thread's row slice (static indices only)
    float4 cch[7];
    bool cvz[7];
#pragma unroll
    for (int j = 0; j < 7; ++j) {
        const int i = tid + j * 1024;
        cvz[j] = (i < NP / 4);
        cch[j] = cvz[j] ? row4[i] : make_float4(0.f, 0.f, 0.f, 0.f);
    }

    const int K0 = min(npos[b] * NEGPOS_I, NP);
    int k = K0;
    unsigned prefix = 0;

    const int shifts[3] = {21, 10, 0};
    const unsigned masks[3] = {0u, 0xFFE00000u, 0xFFFFFC00u};

    for (int pass = 0; pass < 3; ++pass) {
        const int shift = shifts[pass];
        const unsigned mask_hi = masks[pass];
        {
            uint4* hz = (uint4*)hist16;
            for (int j = tid; j < 2048 * 4; j += 1024)
                hz[j] = make_uint4(0u, 0u, 0u, 0u);
        }
        __syncthreads();
#pragma unroll
        for (int j = 0; j < 7; ++j) {
            if (cvz[j]) {
                const float4 v4 = cch[j];
#pragma unroll
                for (int c = 0; c < 4; ++c) {
                    const float f = (c == 0) ? v4.x : (c == 1) ? v4.y
                                  : (c == 2) ? v4.z : v4.w;
                    const unsigned v = __float_as_uint(f);
                    if ((v & mask_hi) == (prefix & mask_hi))
                        atomicAdd(&hist16[(v >> shift) & 2047u][sub], 1u);
                }
            }
        }
        __syncthreads();
        for (int j = tid; j < 2048; j += 1024) {
            const uint4* hp = (const uint4*)&hist16[j][0];
            const uint4 a = hp[0], b4 = hp[1], c4 = hp[2], d4 = hp[3];
            chist[j] = a.x + a.y + a.z + a.w + b4.x + b4.y + b4.z + b4.w +
                       c4.x + c4.y + c4.z + c4.w + d4.x + d4.y + d4.z + d4.w;
        }
        __syncthreads();
        if (tid < 64) {
            unsigned g = 0;
            for (int j = 0; j < 32; ++j) g += chist[lane * 32 + j];
            unsigned T = g;
            for (int d = 1; d < 64; d <<= 1) {
                const unsigned t = __shfl_down(T, d, 64);
                if (lane + d < 64) T += t;
            }
            const unsigned E = T - g;
            const bool hit = (E < (unsigned)k) && ((unsigned)k <= T);
            const unsigned long long msk = __ballot(hit);
            const int wl = __ffsll(msk) - 1;
            if (lane == wl) {
                unsigned cum = E;
                int bsel = lane * 32, kn = k;
                for (int j = 31; j >= 0; --j) {
                    const unsigned c = chist[lane * 32 + j];
                    if (cum + c >= (unsigned)k) {
                        bsel = lane * 32 + j;
                        kn = k - (int)cum;
                        break;
                    }
                    cum += c;
                }
                sh_bucket = bsel;
                sh_knew = kn;
            }
        }
        __syncthreads();
        prefix |= ((unsigned)sh_bucket) << shift;
        k = sh_knew;
        __syncthreads();
    }
    const float T = __uint_as_float(prefix);

    float msum = 0.f;
    int mcnt = 0;
#pragma unroll
    for (int j = 0; j < 7; ++j) {
        if (cvz[j]) {
            const float4 v4 = cch[j];
#pragma unroll
            for (int c = 0; c < 4; ++c) {
                const float f = (c == 0) ? v4.x : (c == 1) ? v4.y
                              : (c == 2) ? v4.z : v4.w;
                if (__float_as_uint(f) > prefix) { msum += f; mcnt++; }
            }
        }
    }
    for (int s = 32; s > 0; s >>= 1) {
        msum += __shfl_down(msum, s, 64);
        mcnt += __shfl_down(mcnt, s, 64);
    }
    if (lane == 0) { wsum[wid] = msum; wcnt[wid] = mcnt; }
    __syncthreads();
    if (tid == 0) {
        float tot = 0.f;
        int cnt = 0;
        for (int w = 0; w < 16; ++w) { tot += wsum[w]; cnt += wcnt[w]; }
        atomicAdd(&accB[b * 2 + 1], tot + (float)(K0 - cnt) * T);
        __threadfence();
        if (atomicAdd(done, 1) == NB - 1) {   // merged k_final
            volatile const float* va = accB;
            volatile const int* vn = npos;
            int n = 0;
            float a0 = 0.f, a1 = 0.f;
            for (int bb = 0; bb < NB; ++bb) {
                n += vn[bb];
                a0 += va[bb * 2 + 0];
                a1 += va[bb * 2 + 1];
            }
            const float N = (float)n;
            out[0] = a0 / N;
            out[1] = a1 / N;
        }
    }
}

extern "C" void kernel_launch(void* const* d_in, const int* in_sizes, int n_in,
                              void* d_out, int out_size, void* d_ws, size_t ws_size,
                              hipStream_t stream) {
    const float* pred   = (const float*)d_in[0];
    const float* tboxes = (const float*)d_in[1];
    const int*   tlabels = (const int*)d_in[2];
    const float* priors = (const float*)d_in[3];
    float* out = (float*)d_out;

    char* w = (char*)d_ws;
    float2* bt2 = (float2*)w;                         // 8*BPCNT bytes
    float*  lrk = (float*)(w + 8ull * BPCNT);         // 4*BPCNT bytes
    u64*    mcand = (u64*)(w + 12ull * BPCNT);        // NB*NO*MBLK2 u64 (100 KB)
    char*   w2 = w + 12ull * BPCNT + 8ull * NB * NO * MBLK2;
    int*    npos = (int*)w2;                          // NB i32
    float*  accB = (float*)(w2 + 4ull * NB);          // NB*2 f32
    int*    done = (int*)(w2 + 4ull * NB + 8ull * NB); // 1 i32

    k_match<<<dim3(MBLK2, NB), dim3(256), 0, stream>>>(
        tboxes, priors, bt2, mcand, npos, accB, done);
    k_main<<<dim3(SPB2, NB), dim3(64), 0, stream>>>(
        pred, tboxes, tlabels, priors, bt2, mcand, lrk, npos, accB);
    k_select<<<dim3(NB), dim3(1024), 0, stream>>>(lrk, npos, accB, done, out);
}